// Round 2
// baseline (128.012 us; speedup 1.0000x reference)
//
#include <hip/hip_runtime.h>
#include <hip/hip_bf16.h>

typedef __attribute__((ext_vector_type(8))) short bf16x8;
typedef __attribute__((ext_vector_type(4))) float f32x4;

#define N      128
#define KTOT   131072
#define BK     64
#define LDT    (BK + 8)   // 72 ushorts = 144 B row stride (16B aligned, not 128B-multiple)

__device__ __forceinline__ ushort f2bf(float f) {
    // round-to-nearest-even fp32 -> bf16 (inputs are finite normals)
    union { float f; unsigned u; } v; v.f = f;
    unsigned u = v.u;
    return (ushort)((u + 0x7fffu + ((u >> 16) & 1u)) >> 16);
}

// ---------------------------------------------------------------------------
// Kernel A: partial Gram. Block b computes C_partial = X[:, kb:kb+KC] * X[:, kb:kb+KC]^T
// 256 threads = 4 waves; wave w owns output tile-rows {2w, 2w+1} x all 8 tile-cols.
// ---------------------------------------------------------------------------
template <bool ATOMIC>
__global__ __launch_bounds__(256) void gram_kernel(const float* __restrict__ X,
                                                   float* __restrict__ out,
                                                   int KC) {
    __shared__ ushort tile[N][LDT];

    const int t    = threadIdx.x;
    const int lane = t & 63;
    const int wv   = t >> 6;
    const int fr   = lane & 15;   // fragment row/col within 16
    const int fh   = lane >> 4;   // k-subgroup 0..3
    const int c4   = t & 15;      // float4 column of the 64-wide stage
    const int r0   = t >> 4;      // 0..15 base row for staging

    const long kbase = (long)blockIdx.x * (long)KC;

    f32x4 acc[2][8];
#pragma unroll
    for (int i = 0; i < 2; ++i)
#pragma unroll
        for (int j = 0; j < 8; ++j)
            acc[i][j] = (f32x4){0.f, 0.f, 0.f, 0.f};

    const int nstages = KC / BK;
    for (int s = 0; s < nstages; ++s) {
        const long kk = kbase + (long)s * BK;
        // stage 128x64 fp32 -> bf16 into LDS (coalesced: 16 lanes = 256B/row)
#pragma unroll
        for (int p = 0; p < 8; ++p) {
            const int row = r0 + p * 16;
            const float4 v = *(const float4*)(X + (long)row * KTOT + kk + c4 * 4);
            ushort4 h;
            h.x = f2bf(v.x); h.y = f2bf(v.y); h.z = f2bf(v.z); h.w = f2bf(v.w);
            *(ushort4*)&tile[row][c4 * 4] = h;
        }
        __syncthreads();

#pragma unroll
        for (int kh = 0; kh < 2; ++kh) {
            bf16x8 bfrag[8];
#pragma unroll
            for (int j = 0; j < 8; ++j)
                bfrag[j] = *(const bf16x8*)&tile[j * 16 + fr][kh * 32 + fh * 8];
#pragma unroll
            for (int i = 0; i < 2; ++i) {
                const bf16x8 afrag = *(const bf16x8*)&tile[(wv * 2 + i) * 16 + fr][kh * 32 + fh * 8];
#pragma unroll
                for (int j = 0; j < 8; ++j)
                    acc[i][j] = __builtin_amdgcn_mfma_f32_16x16x32_bf16(afrag, bfrag[j], acc[i][j], 0, 0, 0);
            }
        }
        __syncthreads();
    }

    // C/D layout (m89-verified): col = lane&15, row = (lane>>4)*4 + reg
    if (ATOMIC) {
#pragma unroll
        for (int i = 0; i < 2; ++i)
#pragma unroll
            for (int j = 0; j < 8; ++j)
#pragma unroll
                for (int r = 0; r < 4; ++r) {
                    const int rg = (wv * 2 + i) * 16 + fh * 4 + r;
                    const int cg = j * 16 + fr;
                    atomicAdd(&out[rg * N + cg], acc[i][j][r]);
                }
    } else {
        float* dst = out + (size_t)blockIdx.x * (size_t)(N * N);
#pragma unroll
        for (int i = 0; i < 2; ++i)
#pragma unroll
            for (int j = 0; j < 8; ++j)
#pragma unroll
                for (int r = 0; r < 4; ++r) {
                    const int rg = (wv * 2 + i) * 16 + fh * 4 + r;
                    const int cg = j * 16 + fr;
                    dst[rg * N + cg] = acc[i][j][r];
                }
    }
}

// ---------------------------------------------------------------------------
// Kernel B: sum NB partial Gram matrices -> C (16384 floats)
// ---------------------------------------------------------------------------
__global__ __launch_bounds__(256) void reduce_kernel(const float* __restrict__ part,
                                                     float* __restrict__ C, int NB) {
    const int j = blockIdx.x * 256 + threadIdx.x;
    float s = 0.f;
#pragma unroll 8
    for (int b = 0; b < NB; ++b)
        s += part[(size_t)b * (size_t)(N * N) + j];
    C[j] = s;
}

// ---------------------------------------------------------------------------
// Kernel C: distances + masked max/min + margin loss (1 block, 128 threads)
// ---------------------------------------------------------------------------
__global__ __launch_bounds__(128) void loss_kernel(const float* __restrict__ C,
                                                   const int* __restrict__ tg,
                                                   float* __restrict__ out) {
    __shared__ float Cs[N][N + 4];
    __shared__ float sqs[N];
    __shared__ int   ts[N];
    __shared__ float red[2];

    const int t = threadIdx.x;  // 0..127
    // stage C into LDS, coalesced float4
#pragma unroll
    for (int it = 0; it < 32; ++it) {
        const int idx = it * 512 + t * 4;
        const float4 v = *(const float4*)(C + idx);
        const int r = idx >> 7;
        const int c = idx & 127;
        Cs[r][c] = v.x; Cs[r][c + 1] = v.y; Cs[r][c + 2] = v.z; Cs[r][c + 3] = v.w;
    }
    ts[t] = tg[t];
    __syncthreads();
    sqs[t] = Cs[t][t];   // diagonal of Gram = row sum of squares
    __syncthreads();

    const int   ti  = ts[t];
    const int   hi  = t >> 6;   // modality
    const float sqi = sqs[t];
    float ap = -INFINITY, an = INFINITY;
#pragma unroll 4
    for (int jj = 0; jj < N; ++jj) {
        const int j = (jj + t) & (N - 1);   // rotate -> 2-way LDS banks max
        const float d2 = sqi + sqs[j] - 2.0f * Cs[t][j];
        const float d  = sqrtf(fmaxf(d2, 1e-12f));
        const bool cross = ((j >> 6) != hi);
        const bool same  = (ts[j] == ti);
        if (cross && same)  ap = fmaxf(ap, d);
        if (cross && !same) an = fminf(an, d);
    }
    float li = fmaxf(ap - an + 0.3f, 0.0f);   // relu; ap=-inf -> 0

#pragma unroll
    for (int off = 32; off > 0; off >>= 1)
        li += __shfl_down(li, off, 64);
    if ((t & 63) == 0) red[t >> 6] = li;
    __syncthreads();
    if (t == 0) out[0] = (red[0] + red[1]) * (1.0f / (float)N);
}

// ---------------------------------------------------------------------------
extern "C" void kernel_launch(void* const* d_in, const int* in_sizes, int n_in,
                              void* d_out, int out_size, void* d_ws, size_t ws_size,
                              hipStream_t stream) {
    const float* X  = (const float*)d_in[0];
    const int*   tg = (const int*)d_in[1];
    float*       out = (float*)d_out;

    const int    NB         = 256;
    const size_t part_elems = (size_t)NB * (size_t)(N * N);          // 4,194,304 floats
    const size_t need       = (part_elems + (size_t)(N * N)) * sizeof(float);

    if (ws_size >= need) {
        float* part = (float*)d_ws;
        float* C    = part + part_elems;
        gram_kernel<false><<<NB, 256, 0, stream>>>(X, part, KTOT / NB);
        reduce_kernel<<<(N * N) / 256, 256, 0, stream>>>(part, C, NB);
        loss_kernel<<<1, 128, 0, stream>>>(C, tg, out);
    } else {
        // small-workspace fallback: atomic accumulation into C (64 KiB)
        float* C = (float*)d_ws;
        hipMemsetAsync(C, 0, (size_t)(N * N) * sizeof(float), stream);
        gram_kernel<true><<<64, 256, 0, stream>>>(X, C, KTOT / 64);
        loss_kernel<<<1, 128, 0, stream>>>(C, tg, out);
    }
}

// Round 4
// 111.142 us; speedup vs baseline: 1.1518x; 1.1518x over previous
//
#include <hip/hip_runtime.h>
#include <hip/hip_bf16.h>

typedef __attribute__((ext_vector_type(8))) short  bf16x8;
typedef __attribute__((ext_vector_type(8))) ushort ushortx8;
typedef __attribute__((ext_vector_type(4))) float  f32x4;

#define N     128
#define KTOT  131072
#define NB    256
#define KC    (KTOT / NB)   // 512
#define BK    64
#define NST   (KC / BK)     // 8
#define LDT   72            // ushorts per LDS row: 144 B stride (16B-aligned, not 128B-multiple)

__device__ __forceinline__ ushort f2bf(float f) {
    // round-to-nearest-even fp32 -> bf16
    union { float f; unsigned u; } v; v.f = f;
    const unsigned u = v.u;
    return (ushort)((u + 0x7fffu + ((u >> 16) & 1u)) >> 16);
}

// ---------------------------------------------------------------------------
// Kernel A: partial Gram. Block b: C_partial = Xb * Xb^T over its K-slice.
// 512 threads = 8 waves; wave w owns output rows [16w,16w+16) x all 128 cols.
// Register-prefetch pipeline: stage s+1's global loads issued before stage s's
// MFMA phase -> 32 KiB in flight per CU (> 9.2 KiB latency-BW product).
// ---------------------------------------------------------------------------
template <bool ATOMIC>
__global__ __launch_bounds__(512) void gram_kernel(const float* __restrict__ X,
                                                   float* __restrict__ out) {
    __shared__ ushort tile[N][LDT];

    const int t    = threadIdx.x;
    const int lane = t & 63;
    const int wv   = t >> 6;     // 0..7: output tile-row
    const int fr   = lane & 15;  // MFMA fragment index within 16
    const int fh   = lane >> 4;  // k-subgroup 0..3
    const int r0   = t >> 4;     // staging base row 0..31 (rows r0+32p)
    const int c4   = t & 15;     // staging float4 column

    const long kbase = (long)blockIdx.x * KC;
    const float* xp = X + kbase + (long)r0 * KTOT + c4 * 4;

    f32x4 acc[8];
#pragma unroll
    for (int j = 0; j < 8; ++j) acc[j] = (f32x4){0.f, 0.f, 0.f, 0.f};

    float4 rg[4], ng[4];
    // prologue: prefetch stage 0 (rows r0 + 32p, 16B each, perfectly coalesced)
#pragma unroll
    for (int p = 0; p < 4; ++p)
        rg[p] = *(const float4*)(xp + (long)(32 * p) * KTOT);

    auto store_stage = [&]() {
#pragma unroll
        for (int p = 0; p < 4; ++p) {
            ushort4 h;
            h.x = f2bf(rg[p].x); h.y = f2bf(rg[p].y);
            h.z = f2bf(rg[p].z); h.w = f2bf(rg[p].w);
            *(ushort4*)&tile[r0 + 32 * p][c4 * 4] = h;
        }
    };
    auto mfma_stage = [&]() {
#pragma unroll
        for (int kh = 0; kh < 2; ++kh) {
            const bf16x8 af = *(const bf16x8*)&tile[wv * 16 + fr][kh * 32 + fh * 8];
#pragma unroll
            for (int j = 0; j < 8; ++j) {
                const bf16x8 bf = *(const bf16x8*)&tile[j * 16 + fr][kh * 32 + fh * 8];
                acc[j] = __builtin_amdgcn_mfma_f32_16x16x32_bf16(af, bf, acc[j], 0, 0, 0);
            }
        }
    };

    for (int s = 0; s < NST - 1; ++s) {
        __syncthreads();           // all waves done reading previous stage
        store_stage();
        // issue next stage's loads now; vmcnt waited only at next store_stage
#pragma unroll
        for (int p = 0; p < 4; ++p)
            ng[p] = *(const float4*)(xp + (long)(s + 1) * BK + (long)(32 * p) * KTOT);
        __syncthreads();           // stage visible to all waves
        mfma_stage();
#pragma unroll
        for (int p = 0; p < 4; ++p) rg[p] = ng[p];
    }
    __syncthreads();
    store_stage();
    __syncthreads();
    mfma_stage();

    // C/D layout (m89-verified): col = lane&15, row = (lane>>4)*4 + reg
    if (ATOMIC) {
#pragma unroll
        for (int j = 0; j < 8; ++j)
#pragma unroll
            for (int r = 0; r < 4; ++r)
                atomicAdd(&out[(wv * 16 + fh * 4 + r) * N + j * 16 + fr], acc[j][r]);
    } else {
        float* dst = out + (size_t)blockIdx.x * (size_t)(N * N);
#pragma unroll
        for (int j = 0; j < 8; ++j)
#pragma unroll
            for (int r = 0; r < 4; ++r)
                dst[(wv * 16 + fh * 4 + r) * N + j * 16 + fr] = acc[j][r];
    }
}

// ---------------------------------------------------------------------------
// Kernel B: sum NB partial Gram matrices -> C. 256 blocks x 256 threads.
// Block owns 64 consecutive floats of C; 8 thread-groups split the NB dim.
// ---------------------------------------------------------------------------
__global__ __launch_bounds__(256) void reduce_kernel(const float* __restrict__ part,
                                                     float* __restrict__ C) {
    __shared__ float2 red[256];
    const int t  = threadIdx.x;
    const int g  = t >> 5;                 // 0..7: partial-group
    const int jo = t & 31;                 // float2 lane within the 64-float chunk
    const size_t jb = (size_t)blockIdx.x * 64;

    float2 s = {0.f, 0.f};
#pragma unroll 8
    for (int b = 0; b < 32; ++b) {
        const float2 v = ((const float2*)(part + (size_t)(g * 32 + b) * (N * N) + jb))[jo];
        s.x += v.x; s.y += v.y;
    }
    red[t] = s;
    __syncthreads();
    if (t < 32) {
        float2 a = red[t];
#pragma unroll
        for (int g2 = 1; g2 < 8; ++g2) {
            const float2 v = red[g2 * 32 + t];
            a.x += v.x; a.y += v.y;
        }
        ((float2*)(C + jb))[t] = a;
    }
}

// ---------------------------------------------------------------------------
// Kernel C: distances + masked max/min + margin loss (1 block, 128 threads)
// ---------------------------------------------------------------------------
__global__ __launch_bounds__(128) void loss_kernel(const float* __restrict__ C,
                                                   const int* __restrict__ tg,
                                                   float* __restrict__ out) {
    __shared__ float Cs[N][N + 4];
    __shared__ float sqs[N];
    __shared__ int   ts[N];
    __shared__ float red[2];

    const int t = threadIdx.x;  // 0..127
#pragma unroll
    for (int it = 0; it < 32; ++it) {
        const int idx = it * 512 + t * 4;
        const float4 v = *(const float4*)(C + idx);
        const int r = idx >> 7;
        const int c = idx & 127;
        Cs[r][c] = v.x; Cs[r][c + 1] = v.y; Cs[r][c + 2] = v.z; Cs[r][c + 3] = v.w;
    }
    ts[t] = tg[t];
    __syncthreads();
    sqs[t] = Cs[t][t];   // diagonal of Gram = row sum of squares
    __syncthreads();

    const int   ti  = ts[t];
    const int   hi  = t >> 6;   // modality
    const float sqi = sqs[t];
    float ap = -INFINITY, an = INFINITY;
#pragma unroll 4
    for (int jj = 0; jj < N; ++jj) {
        const int j = (jj + t) & (N - 1);   // rotate -> spread LDS banks
        const float d2 = sqi + sqs[j] - 2.0f * Cs[t][j];
        const float d  = sqrtf(fmaxf(d2, 1e-12f));
        const bool cross = ((j >> 6) != hi);
        const bool same  = (ts[j] == ti);
        if (cross && same)  ap = fmaxf(ap, d);
        if (cross && !same) an = fminf(an, d);
    }
    float li = fmaxf(ap - an + 0.3f, 0.0f);   // relu; ap=-inf -> 0

#pragma unroll
    for (int off = 32; off > 0; off >>= 1)
        li += __shfl_down(li, off, 64);
    if ((t & 63) == 0) red[t >> 6] = li;
    __syncthreads();
    if (t == 0) out[0] = (red[0] + red[1]) * (1.0f / (float)N);
}

// ---------------------------------------------------------------------------
extern "C" void kernel_launch(void* const* d_in, const int* in_sizes, int n_in,
                              void* d_out, int out_size, void* d_ws, size_t ws_size,
                              hipStream_t stream) {
    const float* X   = (const float*)d_in[0];
    const int*   tg  = (const int*)d_in[1];
    float*       out = (float*)d_out;

    const size_t part_elems = (size_t)NB * (size_t)(N * N);          // 4,194,304 floats
    const size_t need       = (part_elems + (size_t)(N * N)) * sizeof(float);

    if (ws_size >= need) {
        float* part = (float*)d_ws;
        float* C    = part + part_elems;
        gram_kernel<false><<<NB, 512, 0, stream>>>(X, part);
        reduce_kernel<<<(N * N) / 64, 256, 0, stream>>>(part, C);
        loss_kernel<<<1, 128, 0, stream>>>(C, tg, out);
    } else {
        // small-workspace fallback: atomic accumulation into C (64 KiB)
        float* C = (float*)d_ws;
        hipMemsetAsync(C, 0, (size_t)(N * N) * sizeof(float), stream);
        gram_kernel<true><<<NB, 512, 0, stream>>>(X, C);
        loss_kernel<<<1, 128, 0, stream>>>(C, tg, out);
    }
}

// Round 5
// 103.176 us; speedup vs baseline: 1.2407x; 1.0772x over previous
//
#include <hip/hip_runtime.h>
#include <hip/hip_bf16.h>

typedef __attribute__((ext_vector_type(8))) short  bf16x8;
typedef __attribute__((ext_vector_type(4))) float  f32x4;

#define N     128
#define KTOT  131072
#define NB    256
#define KC    (KTOT / NB)   // 512
#define BK    64
#define NST   (KC / BK)     // 8
#define LDT   72            // ushorts per LDS row: 144 B stride (16B-aligned, not 128B-multiple)

__device__ __forceinline__ ushort f2bf(float f) {
    // round-to-nearest-even fp32 -> bf16
    union { float f; unsigned u; } v; v.f = f;
    const unsigned u = v.u;
    return (ushort)((u + 0x7fffu + ((u >> 16) & 1u)) >> 16);
}

// ---------------------------------------------------------------------------
// Kernel A: partial Gram. Block b: C_partial = Xb * Xb^T over its K-slice.
// 512 threads = 8 waves; wave w owns output rows [16w,16w+16) x all 128 cols.
// Double-buffered LDS (ONE barrier/stage) + depth-2 register prefetch:
// store(s) waits on loads issued at s-2 (~2 stages of BW time in flight).
// ---------------------------------------------------------------------------
template <bool ATOMIC>
__global__ __launch_bounds__(512) void gram_kernel(const float* __restrict__ X,
                                                   float* __restrict__ out) {
    __shared__ ushort tile[2][N][LDT];   // 36.9 KB

    const int t    = threadIdx.x;
    const int lane = t & 63;
    const int wv   = t >> 6;     // 0..7: output tile-row
    const int fr   = lane & 15;  // MFMA fragment index within 16
    const int fh   = lane >> 4;  // k-subgroup 0..3
    const int r0   = t >> 4;     // staging base row 0..31 (rows r0+32p)
    const int c4   = t & 15;     // staging float4 column

    const long kbase = (long)blockIdx.x * KC;
    const float* xp = X + kbase + (long)r0 * KTOT + c4 * 4;

    f32x4 acc[8];
#pragma unroll
    for (int j = 0; j < 8; ++j) acc[j] = (f32x4){0.f, 0.f, 0.f, 0.f};

    float4 pf[2][4];
    // prologue: prefetch stages 0 and 1 (rows r0 + 32p, 16B each, coalesced)
#pragma unroll
    for (int p = 0; p < 4; ++p) pf[0][p] = *(const float4*)(xp + (long)(32 * p) * KTOT);
#pragma unroll
    for (int p = 0; p < 4; ++p) pf[1][p] = *(const float4*)(xp + BK + (long)(32 * p) * KTOT);

#pragma unroll
    for (int s = 0; s < NST; ++s) {
        const int cur = s & 1;
        // store stage s (waits vmcnt only on loads issued two stages back)
#pragma unroll
        for (int p = 0; p < 4; ++p) {
            ushort4 h;
            h.x = f2bf(pf[cur][p].x); h.y = f2bf(pf[cur][p].y);
            h.z = f2bf(pf[cur][p].z); h.w = f2bf(pf[cur][p].w);
            *(ushort4*)&tile[cur][r0 + 32 * p][c4 * 4] = h;
        }
        // prefetch stage s+2 into the buffer just freed
        if (s + 2 < NST) {
#pragma unroll
            for (int p = 0; p < 4; ++p)
                pf[cur][p] = *(const float4*)(xp + (long)(s + 2) * BK + (long)(32 * p) * KTOT);
        }
        __syncthreads();   // stage s visible; also fences reads of tile[cur] from stage s-2
#pragma unroll
        for (int kh = 0; kh < 2; ++kh) {
            const bf16x8 af = *(const bf16x8*)&tile[cur][wv * 16 + fr][kh * 32 + fh * 8];
#pragma unroll
            for (int j = 0; j < 8; ++j) {
                const bf16x8 bf = *(const bf16x8*)&tile[cur][j * 16 + fr][kh * 32 + fh * 8];
                acc[j] = __builtin_amdgcn_mfma_f32_16x16x32_bf16(af, bf, acc[j], 0, 0, 0);
            }
        }
    }

    // C/D layout (m89-verified): col = lane&15, row = (lane>>4)*4 + reg
    if (ATOMIC) {
#pragma unroll
        for (int j = 0; j < 8; ++j)
#pragma unroll
            for (int r = 0; r < 4; ++r)
                atomicAdd(&out[(wv * 16 + fh * 4 + r) * N + j * 16 + fr], acc[j][r]);
    } else {
        float* dst = out + (size_t)blockIdx.x * (size_t)(N * N);
#pragma unroll
        for (int j = 0; j < 8; ++j)
#pragma unroll
            for (int r = 0; r < 4; ++r)
                dst[(wv * 16 + fh * 4 + r) * N + j * 16 + fr] = acc[j][r];
    }
}

// ---------------------------------------------------------------------------
// Kernel B: sum NB partial Gram matrices -> C. 256 blocks x 256 threads.
// Block owns 64 consecutive floats of C; 8 thread-groups split the NB dim.
// ---------------------------------------------------------------------------
__global__ __launch_bounds__(256) void reduce_kernel(const float* __restrict__ part,
                                                     float* __restrict__ C) {
    __shared__ float2 red[256];
    const int t  = threadIdx.x;
    const int g  = t >> 5;                 // 0..7: partial-group
    const int jo = t & 31;                 // float2 lane within the 64-float chunk
    const size_t jb = (size_t)blockIdx.x * 64;

    float2 s = {0.f, 0.f};
#pragma unroll 8
    for (int b = 0; b < 32; ++b) {
        const float2 v = ((const float2*)(part + (size_t)(g * 32 + b) * (N * N) + jb))[jo];
        s.x += v.x; s.y += v.y;
    }
    red[t] = s;
    __syncthreads();
    if (t < 32) {
        float2 a = red[t];
#pragma unroll
        for (int g2 = 1; g2 < 8; ++g2) {
            const float2 v = red[g2 * 32 + t];
            a.x += v.x; a.y += v.y;
        }
        ((float2*)(C + jb))[t] = a;
    }
}

// ---------------------------------------------------------------------------
// Kernel C: distances + masked max/min + margin loss (1 block, 256 threads,
// 2 threads per row each scanning half the columns)
// ---------------------------------------------------------------------------
__global__ __launch_bounds__(256) void loss_kernel(const float* __restrict__ C,
                                                   const int* __restrict__ tg,
                                                   float* __restrict__ out) {
    __shared__ float Cs[N][N + 4];
    __shared__ float sqs[N];
    __shared__ int   ts[N];
    __shared__ float aph[N], anh[N];
    __shared__ float red[2];

    const int t = threadIdx.x;  // 0..255
#pragma unroll
    for (int it = 0; it < 16; ++it) {
        const int idx = it * 1024 + t * 4;
        const float4 v = *(const float4*)(C + idx);
        const int r = idx >> 7;
        const int c = idx & 127;
        Cs[r][c] = v.x; Cs[r][c + 1] = v.y; Cs[r][c + 2] = v.z; Cs[r][c + 3] = v.w;
    }
    if (t < N) ts[t] = tg[t];
    __syncthreads();
    if (t < N) sqs[t] = Cs[t][t];   // diagonal of Gram = row sum of squares
    __syncthreads();

    const int   r   = t & 127;   // row
    const int   h2  = t >> 7;    // column half 0/1
    const int   ti  = ts[r];
    const int   hi  = r >> 6;    // modality
    const float sqi = sqs[r];
    float ap = -INFINITY, an = INFINITY;
#pragma unroll 4
    for (int jj = 0; jj < 64; ++jj) {
        const int j = h2 * 64 + ((jj + r) & 63);   // rotate -> spread LDS banks
        const float d2 = sqi + sqs[j] - 2.0f * Cs[r][j];
        const float d  = sqrtf(fmaxf(d2, 1e-12f));
        const bool cross = ((j >> 6) != hi);
        const bool same  = (ts[j] == ti);
        if (cross && same)  ap = fmaxf(ap, d);
        if (cross && !same) an = fminf(an, d);
    }
    if (h2) { aph[r] = ap; anh[r] = an; }
    __syncthreads();
    if (!h2) {
        ap = fmaxf(ap, aph[r]);
        an = fminf(an, anh[r]);
        float li = fmaxf(ap - an + 0.3f, 0.0f);   // relu; ap=-inf -> 0
#pragma unroll
        for (int off = 32; off > 0; off >>= 1)
            li += __shfl_down(li, off, 64);
        if ((r & 63) == 0) red[r >> 6] = li;
    }
    __syncthreads();
    if (t == 0) out[0] = (red[0] + red[1]) * (1.0f / (float)N);
}

// ---------------------------------------------------------------------------
extern "C" void kernel_launch(void* const* d_in, const int* in_sizes, int n_in,
                              void* d_out, int out_size, void* d_ws, size_t ws_size,
                              hipStream_t stream) {
    const float* X   = (const float*)d_in[0];
    const int*   tg  = (const int*)d_in[1];
    float*       out = (float*)d_out;

    const size_t part_elems = (size_t)NB * (size_t)(N * N);          // 4,194,304 floats
    const size_t need       = (part_elems + (size_t)(N * N)) * sizeof(float);

    if (ws_size >= need) {
        float* part = (float*)d_ws;
        float* C    = part + part_elems;
        gram_kernel<false><<<NB, 512, 0, stream>>>(X, part);
        reduce_kernel<<<(N * N) / 64, 256, 0, stream>>>(part, C);
        loss_kernel<<<1, 256, 0, stream>>>(C, tg, out);
    } else {
        // small-workspace fallback: atomic accumulation into C (64 KiB)
        float* C = (float*)d_ws;
        hipMemsetAsync(C, 0, (size_t)(N * N) * sizeof(float), stream);
        gram_kernel<true><<<NB, 512, 0, stream>>>(X, C);
        loss_kernel<<<1, 256, 0, stream>>>(C, tg, out);
    }
}